// Round 8
// baseline (430.993 us; speedup 1.0000x reference)
//
#include <hip/hip_runtime.h>
#include <hip/hip_bf16.h>

typedef float f32x4 __attribute__((ext_vector_type(4)));
typedef short s16x8 __attribute__((ext_vector_type(8)));

using bf16 = __hip_bfloat16;

namespace {
constexpr int KD = 1024;      // 8 * C_IN
constexpr int BK = 32;        // K per MFMA step
constexpr int NT = KD / BK;   // 32
}

__device__ __forceinline__ s16x8 cvt8(f32x4 a, f32x4 b) {
  union { s16x8 v; bf16 h[8]; } u;
#pragma unroll
  for (int j = 0; j < 4; ++j) u.h[j] = __float2bfloat16(a[j]);
#pragma unroll
  for (int j = 0; j < 4; ++j) u.h[j + 4] = __float2bfloat16(b[j]);
  return u.v;
}

// weights [1024][256] fp32 -> Bt [256][1024] bf16 (transposed, MFMA-B friendly)
__global__ void k_transpose_w(const float* __restrict__ w, bf16* __restrict__ bt) {
  int t = blockIdx.x * 256 + threadIdx.x;   // 32768 threads
  int n = t & 255;
  int k0 = (t >> 8) << 3;
  union { s16x8 v; bf16 h[8]; } u;
#pragma unroll
  for (int j = 0; j < 8; ++j)
    u.h[j] = __float2bfloat16(w[(size_t)(k0 + j) * 256 + n]);
  *(s16x8*)(bt + (size_t)n * KD + k0) = u.v;
}

__global__ void k_clear_flags(int* __restrict__ flags, int np4) {
  int i = blockIdx.x * 256 + threadIdx.x;
  if (i < np4) ((int4*)flags)[i] = make_int4(0, 0, 0, 0);
}

__global__ void k_set_flags(const int* __restrict__ idx, int* __restrict__ flags, int m) {
  int i = blockIdx.x * 256 + threadIdx.x;
  if (i < m) flags[idx[i]] = 1;
}

// Fused GEMM + zero-fill. NO LDS, NO barriers, NO DMA, NO inline asm.
// Each wave owns a 64(M)x64(N) tile. Register PING-PONG pipeline: iter t
// loads A(t+1) into the buffer consumed at t+1 -> cross-iteration dataflow
// forces the loads to stay in flight across the body (the compiler cannot
// collapse the depth, and its auto-vmcnt is exactly counted for its own
// loads). 4 sibling waves share A rows via L1/L2 (A read from HBM once).
// B fragments come from the L2-resident 512 KB transposed weights.
// Every 5th block zeros the empty parent rows (disjoint rows, order-free).
__global__ __launch_bounds__(256, 2)
void k_fused(const float* __restrict__ A, const bf16* __restrict__ Bt,
             const int* __restrict__ idx, const int* __restrict__ flags,
             float* __restrict__ out, int NP, int ZBtot) {
  const int bid = blockIdx.x;
  const int lane = threadIdx.x & 63;
  const int wave = threadIdx.x >> 6;   // 0..3

  if ((bid % 5) == 4) {                // ---- zero-fill path ----
    const int zb = bid / 5;            // 0..ZBtot-1
    const f32x4 z = {0.f, 0.f, 0.f, 0.f};
    const int stride = ZBtot * 4;
    for (int row = zb * 4 + wave; row < NP; row += stride) {
      if (flags[row] == 0)
        *(f32x4*)(out + (size_t)row * 256 + lane * 4) = z;
    }
    return;
  }

  // ---- GEMM path ----
  const int gid = bid - bid / 5;       // 0..MT-1 (64-row tile)
  const size_t m0 = (size_t)gid * 64;
  const int n0 = wave * 64;

  // 16x16x32 fragment ownership: row = lane&15, k-octet = lane>>4
  const int r = lane & 15;
  const int kc = lane >> 4;

  const float* ap = A + (m0 + r) * KD + kc * 8;             // A[m0+r][kc*8]
  const bf16*  bp = Bt + (size_t)(n0 + r) * KD + kc * 8;    // Bt[n0+r][kc*8]

  f32x4 acc[4][4] = {};

  f32x4 aP[4][2], aQ[4][2];            // ping-pong A-fragment buffers
  // prologue: A(0) -> aP
#pragma unroll
  for (int fm = 0; fm < 4; ++fm) {
    aP[fm][0] = *(const f32x4*)(ap + (size_t)fm * 16 * KD);
    aP[fm][1] = *(const f32x4*)(ap + (size_t)fm * 16 * KD + 4);
  }

  auto step = [&](f32x4 (&aC)[4][2], f32x4 (&aN)[4][2], int t) {
    // B(t) fragments (L2-resident); auto-wait for these is counted against
    // the A(t+1) loads issued below and keeps them in flight.
    s16x8 bv0 = *(const s16x8*)(bp + (size_t)0 * 16 * KD + t * BK);
    s16x8 bv1 = *(const s16x8*)(bp + (size_t)16 * KD + t * BK);
    s16x8 bv2 = *(const s16x8*)(bp + (size_t)32 * KD + t * BK);
    s16x8 bv3 = *(const s16x8*)(bp + (size_t)48 * KD + t * BK);
    // A(t+1) -> aN (consumed NEXT iter: forced cross-iter liveness)
    if (t + 1 < NT) {
#pragma unroll
      for (int fm = 0; fm < 4; ++fm) {
        aN[fm][0] = *(const f32x4*)(ap + (size_t)fm * 16 * KD + (t + 1) * BK);
        aN[fm][1] = *(const f32x4*)(ap + (size_t)fm * 16 * KD + (t + 1) * BK + 4);
      }
    }
    // consume A(t) from aC
#pragma unroll
    for (int fm = 0; fm < 4; ++fm) {
      s16x8 af = cvt8(aC[fm][0], aC[fm][1]);
      acc[fm][0] = __builtin_amdgcn_mfma_f32_16x16x32_bf16(af, bv0, acc[fm][0], 0, 0, 0);
      acc[fm][1] = __builtin_amdgcn_mfma_f32_16x16x32_bf16(af, bv1, acc[fm][1], 0, 0, 0);
      acc[fm][2] = __builtin_amdgcn_mfma_f32_16x16x32_bf16(af, bv2, acc[fm][2], 0, 0, 0);
      acc[fm][3] = __builtin_amdgcn_mfma_f32_16x16x32_bf16(af, bv3, acc[fm][3], 0, 0, 0);
    }
  };

#pragma unroll 1
  for (int t = 0; t < NT; t += 2) {    // manual 2x body: all indices static
    step(aP, aQ, t);
    step(aQ, aP, t + 1);
  }

  // ---- epilogue: C/D layout col = lane&15, row = (lane>>4)*4 + j ----
  const int col0 = n0 + r;
#pragma unroll
  for (int fm = 0; fm < 4; ++fm) {
    const int4 rows = *(const int4*)(idx + m0 + fm * 16 + kc * 4);
    const int rj[4] = {rows.x, rows.y, rows.z, rows.w};
#pragma unroll
    for (int j = 0; j < 4; ++j) {
      float* op = out + (size_t)rj[j] * 256 + col0;
#pragma unroll
      for (int fn = 0; fn < 4; ++fn)
        op[fn * 16] = acc[fm][fn][j];
    }
  }
}

extern "C" void kernel_launch(void* const* d_in, const int* in_sizes, int n_in,
                              void* d_out, int out_size, void* d_ws, size_t ws_size,
                              hipStream_t stream) {
  const float* data = (const float*)d_in[0];   // [N, 128] == [M, 1024]
  const float* w    = (const float*)d_in[1];   // [8,128,256] == [1024, 256]
  const int*   idx  = (const int*)d_in[2];     // [M] sorted unique parent slots
  float* out = (float*)d_out;                  // [NP, 256]

  const int M  = in_sizes[2];        // 131072
  const int NP = out_size / 256;     // 262144

  int* flags = (int*)d_ws;                                    // NP ints (1 MB)
  bf16* bt = (bf16*)((char*)d_ws + (size_t)NP * sizeof(int)); // 512 KB

  const int MT = M / 64;             // 2048 GEMM tiles
  const int ZB = MT / 4;             // 512 zeroer blocks (every 5th block)
  const int TOT = MT + ZB;           // 2560

  k_transpose_w<<<128, 256, 0, stream>>>(w, bt);
  k_clear_flags<<<(NP / 4 + 255) / 256, 256, 0, stream>>>(flags, NP / 4);
  k_set_flags<<<(M + 255) / 256, 256, 0, stream>>>(idx, flags, M);
  k_fused<<<TOT, 256, 0, stream>>>(data, bt, idx, flags, out, NP, ZB);
}

// Round 9
// 298.181 us; speedup vs baseline: 1.4454x; 1.4454x over previous
//
#include <hip/hip_runtime.h>
#include <hip/hip_bf16.h>

typedef float f32x4 __attribute__((ext_vector_type(4)));
typedef short s16x8 __attribute__((ext_vector_type(8)));

using bf16 = __hip_bfloat16;

namespace {
constexpr int KD = 1024;            // 8 * C_IN
constexpr int BM = 128;
constexpr int BK = 32;
constexpr int NT = KD / BK;         // 32 K-tiles
constexpr int MBLK = 131072 / BM;   // 1024 GEMM blocks
constexpr int ZBLK = 512;           // zero-fill blocks (interleaved)
}

__device__ __forceinline__ s16x8 cvt8(f32x4 a, f32x4 b) {
  union { s16x8 v; bf16 h[8]; } u;
#pragma unroll
  for (int j = 0; j < 4; ++j) u.h[j] = __float2bfloat16(a[j]);
#pragma unroll
  for (int j = 0; j < 4; ++j) u.h[j + 4] = __float2bfloat16(b[j]);
  return u.v;
}

// weights [1024][256] fp32 -> Bt [256][1024] bf16 (transposed, MFMA-B friendly)
__global__ void k_transpose_w(const float* __restrict__ w, bf16* __restrict__ bt) {
  int t = blockIdx.x * 256 + threadIdx.x;   // 32768 threads
  int n = t & 255;
  int k0 = (t >> 8) << 3;
  union { s16x8 v; bf16 h[8]; } u;
#pragma unroll
  for (int j = 0; j < 8; ++j)
    u.h[j] = __float2bfloat16(w[(size_t)(k0 + j) * 256 + n]);
  *(s16x8*)(bt + (size_t)n * KD + k0) = u.v;
}

__global__ void k_clear_flags(int* __restrict__ flags, int np4) {
  int i = blockIdx.x * 256 + threadIdx.x;
  if (i < np4) ((int4*)flags)[i] = make_int4(0, 0, 0, 0);
}

__global__ void k_set_flags(const int* __restrict__ idx, int* __restrict__ flags, int m) {
  int i = blockIdx.x * 256 + threadIdx.x;
  if (i < m) flags[idx[i]] = 1;
}

// Fused GEMM + zero-fill.
// A: global(fp32) -> regs -> cvt bf16 -> ds_write, 2-DEEP pipeline (load
//    A(t+2) at iter t, write A(t+1)): HBM latency spans a full iteration.
//    sched_barrier(0) fences pin issue order so the compiler cannot sink the
//    staging loads (R8: it deleted the ping-pong; VGPR 84 proved it).
// B: direct L2->reg, issued FIRST each iter so its auto-wait is vmcnt(2)
//    and never retires... only older A-stream entries already due.
// Barrier: raw s_barrier preceded by lgkmcnt(0) ONLY — staging regs are
//    private, so NO vmcnt drain anywhere in the loop.
// LDS: A-only, bf16, 2 x 8 KB; swizzle slot = row*4 + (c ^ ((row>>1)&3))
//    -> 2-way max on both write and read (free).
// bid%3==2 blocks zero empty parent rows (disjoint rows -> order-free).
__global__ __launch_bounds__(512, 4)
void k_fused(const float* __restrict__ A, const bf16* __restrict__ Bt,
             const int* __restrict__ idx, const int* __restrict__ flags,
             float* __restrict__ out, int NP) {
  __shared__ bf16 As[2][BM * BK];     // 2 x 8 KB

  const int tid = threadIdx.x;
  const int lane = tid & 63;
  const int wave = tid >> 6;          // 0..7
  const int bid = blockIdx.x;

  if (bid % 3 == 2) {                 // ---- zero-fill path ----
    const int zb = bid / 3;           // 0..ZBLK-1
    const f32x4 z = {0.f, 0.f, 0.f, 0.f};
    for (int row = zb * 8 + wave; row < NP; row += ZBLK * 8) {
      if (flags[row] == 0)
        *(f32x4*)(out + (size_t)row * 256 + lane * 4) = z;
    }
    return;
  }

  // ---- GEMM path ----
  const int gid = (bid / 3) * 2 + (bid % 3);   // 0..MBLK-1
  const int m0 = gid * BM;
  const int wm = wave >> 2;           // 0..1 (row half)
  const int wn = wave & 3;            // 0..3 (col quarter)

  // staging: thread -> (row = tid>>2, chunk = tid&3), 8 f32 per thread
  const int srow = tid >> 2;          // 0..127
  const int sc = tid & 3;             // 0..3
  const float* aSrc = A + (size_t)(m0 + srow) * KD + sc * 8;
  const int sSlot = srow * 4 + (sc ^ ((srow >> 1) & 3));   // 16B slots

  // fragment coords (16x16x32: lane -> row l&15, k-octet l>>4)
  const int r = lane & 15;
  const int kc = lane >> 4;
  const int arow = wm * 64 + r;
  // one b128 per fm (bf16 frag); fm row-stride 16 keeps swizzle bits fixed
  const int aRd = (arow * 4 + (kc ^ ((arow >> 1) & 3))) * 8;  // bf16 idx

  const bf16* bp = Bt + (size_t)(wn * 64 + r) * KD + kc * 8;

  f32x4 acc[4][4] = {};

  // ---- prologue: A(0) -> buf0; A(1) -> X regs ----
  f32x4 x0, x1, y0, y1;
  {
    f32x4 p0 = *(const f32x4*)(aSrc);
    f32x4 p1 = *(const f32x4*)(aSrc + 4);
    x0 = *(const f32x4*)(aSrc + BK);
    x1 = *(const f32x4*)(aSrc + BK + 4);
    *(s16x8*)(&As[0][sSlot * 8]) = cvt8(p0, p1);   // waits p only (vmcnt(2))
    asm volatile("s_waitcnt lgkmcnt(0)" ::: "memory");
    __builtin_amdgcn_sched_barrier(0);
    __builtin_amdgcn_s_barrier();
  }

  // one K-step: consumes buf (t&1) and reg-set C (=A(t+1)); loads A(t+2)
  // into reg-set N; writes C into buf ((t+1)&1).
  auto step = [&](int t, f32x4& c0, f32x4& c1, f32x4& n0, f32x4& n1) {
    // B(t) FIRST: its auto-wait is vmcnt(2) (only the N-loads are newer)
    s16x8 bv0 = *(const s16x8*)(bp + t * BK);
    s16x8 bv1 = *(const s16x8*)(bp + (size_t)16 * KD + t * BK);
    s16x8 bv2 = *(const s16x8*)(bp + (size_t)32 * KD + t * BK);
    s16x8 bv3 = *(const s16x8*)(bp + (size_t)48 * KD + t * BK);
    __builtin_amdgcn_sched_barrier(0);
    if (t + 2 < NT) {                 // A(t+2) -> N
      n0 = *(const f32x4*)(aSrc + (t + 2) * BK);
      n1 = *(const f32x4*)(aSrc + (t + 2) * BK + 4);
    }
    __builtin_amdgcn_sched_barrier(0);

    const int cur = t & 1;
#pragma unroll
    for (int fm = 0; fm < 4; ++fm) {
      s16x8 af = *(const s16x8*)(&As[cur][aRd + fm * 512]);
      acc[fm][0] = __builtin_amdgcn_mfma_f32_16x16x32_bf16(af, bv0, acc[fm][0], 0, 0, 0);
      acc[fm][1] = __builtin_amdgcn_mfma_f32_16x16x32_bf16(af, bv1, acc[fm][1], 0, 0, 0);
      acc[fm][2] = __builtin_amdgcn_mfma_f32_16x16x32_bf16(af, bv2, acc[fm][2], 0, 0, 0);
      acc[fm][3] = __builtin_amdgcn_mfma_f32_16x16x32_bf16(af, bv3, acc[fm][3], 0, 0, 0);
    }
    __builtin_amdgcn_sched_barrier(0);

    if (t + 1 < NT)                   // A(t+1): C -> buf ((t+1)&1)
      *(s16x8*)(&As[cur ^ 1][sSlot * 8]) = cvt8(c0, c1);
    asm volatile("s_waitcnt lgkmcnt(0)" ::: "memory");
    __builtin_amdgcn_sched_barrier(0);
    __builtin_amdgcn_s_barrier();
  };

#pragma unroll 1
  for (int t = 0; t < NT; t += 2) {   // manual 2x: all reg names static
    step(t,     x0, x1, y0, y1);      // consume X, prefetch into Y
    step(t + 1, y0, y1, x0, x1);      // consume Y, prefetch into X
  }

  // ---- epilogue: C/D layout col = lane&15, row = (lane>>4)*4 + j ----
  const int col0 = wn * 64 + r;
  const int rb = m0 + wm * 64 + (kc << 2);
#pragma unroll
  for (int fm = 0; fm < 4; ++fm) {
    const int4 rows = *(const int4*)(idx + rb + fm * 16);
    const int rj[4] = {rows.x, rows.y, rows.z, rows.w};
#pragma unroll
    for (int j = 0; j < 4; ++j) {
      float* op = out + (size_t)rj[j] * 256 + col0;
#pragma unroll
      for (int fn = 0; fn < 4; ++fn)
        op[fn * 16] = acc[fm][fn][j];
    }
  }
}

extern "C" void kernel_launch(void* const* d_in, const int* in_sizes, int n_in,
                              void* d_out, int out_size, void* d_ws, size_t ws_size,
                              hipStream_t stream) {
  const float* data = (const float*)d_in[0];   // [N, 128] == [M, 1024]
  const float* w    = (const float*)d_in[1];   // [8,128,256] == [1024, 256]
  const int*   idx  = (const int*)d_in[2];     // [M] sorted unique parent slots
  float* out = (float*)d_out;                  // [NP, 256]

  const int M  = in_sizes[2];        // 131072
  const int NP = out_size / 256;     // 262144

  int* flags = (int*)d_ws;                                    // NP ints (1 MB)
  bf16* bt = (bf16*)((char*)d_ws + (size_t)NP * sizeof(int)); // 512 KB

  k_transpose_w<<<128, 256, 0, stream>>>(w, bt);
  k_clear_flags<<<(NP / 4 + 255) / 256, 256, 0, stream>>>(flags, NP / 4);
  k_set_flags<<<(M + 255) / 256, 256, 0, stream>>>(idx, flags, M);
  // grid = 1024 GEMM + 512 zero blocks, zeroers interleaved at bid%3==2
  k_fused<<<MBLK + ZBLK, 512, 0, stream>>>(data, bt, idx, flags, out, NP);
}